// Round 1
// baseline (1454.492 us; speedup 1.0000x reference)
//
#include <hip/hip_runtime.h>

#define D0 64
#define D1 1024
#define D2 1024
#define COEFF 0.05f

// One block = one contiguous row of D2=1024 floats at (d0, d1).
// 256 threads x float4. Row staged in LDS for the axis-2 gradient.
__global__ __launch_bounds__(256) void diffusion_step(const float* __restrict__ src,
                                                      float* __restrict__ dst) {
    __shared__ float row[D2];

    const int bid = blockIdx.x;
    const int d1  = bid & (D1 - 1);
    const int d0  = bid >> 10;          // D1 == 1024
    const int t   = threadIdx.x;

    const size_t plane   = (size_t)D1 * D2;
    const size_t rowbase = (size_t)d0 * plane + (size_t)d1 * D2;

    // Center row (coalesced float4), staged to LDS.
    const float4 c = reinterpret_cast<const float4*>(src + rowbase)[t];
    reinterpret_cast<float4*>(row)[t] = c;

    // Axis-1 (d1) neighbors: clamped index + boundary scale.
    const int   ym = (d1 == 0)      ? 0      : d1 - 1;
    const int   yp = (d1 == D1 - 1) ? D1 - 1 : d1 + 1;
    const float sy = (d1 == 0 || d1 == D1 - 1) ? 1.0f : 0.5f;
    const float4 rym = reinterpret_cast<const float4*>(src + (size_t)d0 * plane + (size_t)ym * D2)[t];
    const float4 ryp = reinterpret_cast<const float4*>(src + (size_t)d0 * plane + (size_t)yp * D2)[t];

    // Axis-0 (d0) neighbors.
    const int   zm = (d0 == 0)      ? 0      : d0 - 1;
    const int   zp = (d0 == D0 - 1) ? D0 - 1 : d0 + 1;
    const float sz = (d0 == 0 || d0 == D0 - 1) ? 1.0f : 0.5f;
    const float4 rzm = reinterpret_cast<const float4*>(src + (size_t)zm * plane + (size_t)d1 * D2)[t];
    const float4 rzp = reinterpret_cast<const float4*>(src + (size_t)zp * plane + (size_t)d1 * D2)[t];

    __syncthreads();

    // Axis-2 gradient from the LDS row (clamped idx + scale).
    const int j0 = t * 4;
    float g2[4];
#pragma unroll
    for (int j = 0; j < 4; ++j) {
        const int   idx = j0 + j;
        const int   xm  = (idx == 0)      ? 0      : idx - 1;
        const int   xp  = (idx == D2 - 1) ? D2 - 1 : idx + 1;
        const float sx  = (idx == 0 || idx == D2 - 1) ? 1.0f : 0.5f;
        g2[j] = sx * (row[xp] - row[xm]);
    }

    float4 o;
    o.x = c.x + COEFF * (g2[0] + sy * (ryp.x - rym.x) + sz * (rzp.x - rzm.x));
    o.y = c.y + COEFF * (g2[1] + sy * (ryp.y - rym.y) + sz * (rzp.y - rzm.y));
    o.z = c.z + COEFF * (g2[2] + sy * (ryp.z - rym.z) + sz * (rzp.z - rzm.z));
    o.w = c.w + COEFF * (g2[3] + sy * (ryp.w - rym.w) + sz * (rzp.w - rzm.w));

    reinterpret_cast<float4*>(dst + rowbase)[t] = o;
}

extern "C" void kernel_launch(void* const* d_in, const int* in_sizes, int n_in,
                              void* d_out, int out_size, void* d_ws, size_t ws_size,
                              hipStream_t stream) {
    const float* x   = (const float*)d_in[0];
    float*       out = (float*)d_out;
    float*       ws  = (float*)d_ws;

    const dim3 grid(D0 * D1);
    const dim3 block(256);

    // Ping-pong: iter 0: d_in -> ws; odd iters -> out; even iters -> ws.
    // Iteration 9 (last, odd) writes d_out.
    const float* src = x;
    for (int i = 0; i < 10; ++i) {
        float* dst = (i & 1) ? out : ws;
        diffusion_step<<<grid, block, 0, stream>>>(src, dst);
        src = dst;
    }
}

// Round 2
// 1152.597 us; speedup vs baseline: 1.2619x; 1.2619x over previous
//
#include <hip/hip_runtime.h>

#define D0 64
#define D1 1024
#define D2 1024
#define KST 5                 // fused timesteps per pass
#define E   32                // working tile extent (incl. halo)
#define TT  22                // valid output tile = E - 2*KST
#define NTL 47                // ceil(D1/TT)
#define COEFF 0.05f           // ALPHA * DT
#define PLANE ((size_t)D1 * (size_t)D2)

__device__ __forceinline__ int clampi(int v, int lo, int hi) {
    v = v < lo ? lo : v;
    return v > hi ? hi : v;
}
__device__ __forceinline__ float4 ld4s(const float* p) {
    return *reinterpret_cast<const float4*>(p);
}
__device__ __forceinline__ void st4s(float* p, float4 v) {
    *reinterpret_cast<float4*>(p) = v;
}

// One fused-stencil update for a 1x4 run of points.
// c  = center values (prev stage, plane p) ; zm/zp = prev stage planes p-1/p+1
// up/dn = prev stage plane p, rows ci-1/ci+1 (same col run)
// Boundary semantics (torch.gradient): one-sided diff (scale 1) at global
// edges, central (scale 0.5) in the interior, via clamped-value selects.
__device__ __forceinline__ float4 stencil_pt(float4 c, float4 zm, float4 zp,
                                             float4 up, float4 dn, float szf,
                                             float sy, bool y_lo, bool y_hi,
                                             bool fix2, int g2b) {
    float4 ym = y_lo ? c : up;    // value at clamp(g1-1)
    float4 yp = y_hi ? c : dn;    // value at clamp(g1+1)
    float lx = __shfl_up(c.w, 1);    // left neighbor's last element
    float rx = __shfl_down(c.x, 1);  // right neighbor's first element
    float4 xm = make_float4(lx, c.x, c.y, c.z);
    float4 xp = make_float4(c.y, c.z, c.w, rx);
    float sx0 = 0.5f, sx1 = 0.5f, sx2 = 0.5f, sx3 = 0.5f;
    if (fix2) {   // only blocks touching a d2 volume edge
        if (g2b + 0 == 0) { xm.x = c.x; sx0 = 1.0f; }
        if (g2b + 1 == 0) { xm.y = c.y; sx1 = 1.0f; }
        if (g2b + 2 == 0) { xm.z = c.z; sx2 = 1.0f; }
        if (g2b + 3 == 0) { xm.w = c.w; sx3 = 1.0f; }
        if (g2b + 0 == D2 - 1) { xp.x = c.x; sx0 = 1.0f; }
        if (g2b + 1 == D2 - 1) { xp.y = c.y; sx1 = 1.0f; }
        if (g2b + 2 == D2 - 1) { xp.z = c.z; sx2 = 1.0f; }
        if (g2b + 3 == D2 - 1) { xp.w = c.w; sx3 = 1.0f; }
    }
    float4 o;
    o.x = c.x + COEFF * (sx0 * (xp.x - xm.x) + sy * (yp.x - ym.x) + szf * (zp.x - zm.x));
    o.y = c.y + COEFF * (sx1 * (xp.y - xm.y) + sy * (yp.y - ym.y) + szf * (zp.y - zm.y));
    o.z = c.z + COEFF * (sx2 * (xp.z - xm.z) + sy * (yp.z - ym.z) + szf * (zp.z - zm.z));
    o.w = c.w + COEFF * (sx3 * (xp.w - xm.w) + sy * (yp.w - ym.w) + szf * (zp.w - zm.w));
    return o;
}

__device__ __forceinline__ float4 load_plane_f(const float* __restrict__ src, int zi,
                                               int h1, int h2, int lr, int lc4,
                                               bool edge2load) {
    const int gr = clampi(h1 + lr, 0, D1 - 1);
    const float* rp = src + (size_t)zi * PLANE + (size_t)gr * D2;
    if (!edge2load) return ld4s(rp + (h2 + lc4));
    float4 v;
    v.x = rp[clampi(h2 + lc4 + 0, 0, D2 - 1)];
    v.y = rp[clampi(h2 + lc4 + 1, 0, D2 - 1)];
    v.z = rp[clampi(h2 + lc4 + 2, 0, D2 - 1)];
    v.w = rp[clampi(h2 + lc4 + 3, 0, D2 - 1)];
    return v;
}

// K=5 fused diffusion steps, streaming d0 with a lag-2 stage pipeline.
// ring[0] = input planes; ring[s] = stage-s output planes (s=1..4), 3 slots each.
// Each stage's own z-history lives in registers (l0=newest, l1, l2).
__global__ __launch_bounds__(256) void diffusion_fused(const float* __restrict__ src,
                                                       float* __restrict__ dst) {
    __shared__ __align__(16) float ring[KST][3][E * E];   // 61440 B

    const int b = blockIdx.x;
    const int bt1 = b / NTL;
    const int bt2 = b - bt1 * NTL;
    const int o1 = min(bt1 * TT, D1 - TT);   // output tile origin (overlap-clamped)
    const int o2 = min(bt2 * TT, D2 - TT);
    const int h1 = o1 - KST;                 // halo origin (may be < 0)
    const int h2 = o2 - KST;

    const int tid = threadIdx.x;
    // compute-task mapping: rows 1..30, col runs of 4 (tid<240)
    const int ci = 1 + (tid >> 3);
    const int cj4 = (tid & 7) << 2;
    const bool hasTask = (ci <= E - 2);
    const int g1 = h1 + ci;
    const int g2b = h2 + cj4;
    // load-task mapping: full 32x32 plane
    const int lr = tid >> 3;
    const int lc4 = (tid & 7) << 2;

    const bool edge2load = (h2 < 0) || (h2 + E > D2);
    const bool fix2 = (o2 == 0) || (o2 == D2 - TT);

    const float sy = (g1 == 0 || g1 == D1 - 1) ? 1.0f : 0.5f;
    const bool y_lo = (g1 == 0);
    const bool y_hi = (g1 == D1 - 1);

    const float4 zf4 = make_float4(0.f, 0.f, 0.f, 0.f);
    float4 s1l0 = zf4, s1l1 = zf4, s1l2 = zf4;
    float4 s2l0 = zf4, s2l1 = zf4, s2l2 = zf4;
    float4 s3l0 = zf4, s3l1 = zf4, s3l2 = zf4;
    float4 s4l0 = zf4, s4l1 = zf4, s4l2 = zf4;

    // prefetch input plane 0
    float4 nxt = load_plane_f(src, 0, h1, h2, lr, lc4, edge2load);

#pragma unroll 1
    for (int t = 0; t <= D0 - 1 + 2 * KST; ++t) {
        // ---- phase A: all stage computes (read planes written in prior steps) ----
        if (hasTask) {
            float4 nv1 = s1l0, nv2 = s2l0, nv3 = s3l0, nv4 = s4l0;

            // ---- stage 1: input ring -> ring[1] ----
            {
                const int p = t - 2;
                if (p >= 0 && p <= D0 - 1) {
                    const float* pc = ring[0][p % 3];
                    const float* pm = ring[0][(p > 0 ? p - 1 : 0) % 3];
                    const float* pp = ring[0][(p < D0 - 1 ? p + 1 : D0 - 1) % 3];
                    float4 c  = ld4s(pc + ci * E + cj4);
                    float4 zm = ld4s(pm + ci * E + cj4);
                    float4 zp = ld4s(pp + ci * E + cj4);
                    float4 up = ld4s(pc + (ci - 1) * E + cj4);
                    float4 dn = ld4s(pc + (ci + 1) * E + cj4);
                    const float szf = (p == 0 || p == D0 - 1) ? 1.0f : 0.5f;
                    nv1 = stencil_pt(c, zm, zp, up, dn, szf, sy, y_lo, y_hi, fix2, g2b);
                    st4s(&ring[1][p % 3][ci * E + cj4], nv1);
                }
            }

#define MID_STAGE(SNUM, LAG0, LAG1, LAG2, NV)                                       \
            {                                                                       \
                const int p = t - 2 * SNUM;                                         \
                if (p >= 0 && p <= D0 - 1) {                                        \
                    const float* pl = ring[SNUM - 1][p % 3];                        \
                    float4 c  = LAG1;                                               \
                    float4 zm = (p == 0) ? c : LAG2;                                \
                    float4 zp = (p == D0 - 1) ? c : LAG0;                           \
                    float4 up = ld4s(pl + (ci - 1) * E + cj4);                      \
                    float4 dn = ld4s(pl + (ci + 1) * E + cj4);                      \
                    const float szf = (p == 0 || p == D0 - 1) ? 1.0f : 0.5f;        \
                    NV = stencil_pt(c, zm, zp, up, dn, szf, sy, y_lo, y_hi, fix2, g2b); \
                    st4s(&ring[SNUM][p % 3][ci * E + cj4], NV);                     \
                }                                                                   \
            }
            MID_STAGE(2, s1l0, s1l1, s1l2, nv2)
            MID_STAGE(3, s2l0, s2l1, s2l2, nv3)
            MID_STAGE(4, s3l0, s3l1, s3l2, nv4)
#undef MID_STAGE

            // ---- stage 5: ring[4] + s4 lags -> global ----
            {
                const int p = t - 2 * KST;
                if (p >= 0 && p <= D0 - 1 && ci >= KST && ci < E - KST) {
                    const float* pl = ring[4][p % 3];
                    float4 c  = s4l1;
                    float4 zm = (p == 0) ? c : s4l2;
                    float4 zp = (p == D0 - 1) ? c : s4l0;
                    float4 up = ld4s(pl + (ci - 1) * E + cj4);
                    float4 dn = ld4s(pl + (ci + 1) * E + cj4);
                    const float szf = (p == 0 || p == D0 - 1) ? 1.0f : 0.5f;
                    float4 o = stencil_pt(c, zm, zp, up, dn, szf, sy, y_lo, y_hi, fix2, g2b);
                    const size_t ob = (size_t)p * PLANE + (size_t)g1 * D2;
                    if (cj4 > KST - 1 && cj4 + 3 < E - KST) {   // fully-valid run
                        st4s(&dst[ob + g2b], o);
                    } else {
                        if (cj4 + 0 >= KST && cj4 + 0 < E - KST) dst[ob + g2b + 0] = o.x;
                        if (cj4 + 1 >= KST && cj4 + 1 < E - KST) dst[ob + g2b + 1] = o.y;
                        if (cj4 + 2 >= KST && cj4 + 2 < E - KST) dst[ob + g2b + 2] = o.z;
                        if (cj4 + 3 >= KST && cj4 + 3 < E - KST) dst[ob + g2b + 3] = o.w;
                    }
                }
            }

            // ---- roll lag registers (freeze-rolls keep l0 when inactive) ----
            s1l2 = s1l1; s1l1 = s1l0; s1l0 = nv1;
            s2l2 = s2l1; s2l1 = s2l0; s2l0 = nv2;
            s3l2 = s3l1; s3l1 = s3l0; s3l0 = nv3;
            s4l2 = s4l1; s4l1 = s4l0; s4l0 = nv4;
        }

        __syncthreads();
        // ---- phase B: commit prefetched input plane t, issue load of t+1 ----
        if (t <= D0 - 1) st4s(&ring[0][t % 3][lr * E + lc4], nxt);
        if (t + 1 <= D0 - 1) nxt = load_plane_f(src, t + 1, h1, h2, lr, lc4, edge2load);
        __syncthreads();
    }
}

extern "C" void kernel_launch(void* const* d_in, const int* in_sizes, int n_in,
                              void* d_out, int out_size, void* d_ws, size_t ws_size,
                              hipStream_t stream) {
    const float* x   = (const float*)d_in[0];
    float*       out = (float*)d_out;
    float*       ws  = (float*)d_ws;

    const dim3 grid(NTL * NTL);   // 2209 blocks
    const dim3 block(256);

    // 10 steps = 2 fused passes of 5
    diffusion_fused<<<grid, block, 0, stream>>>(x, ws);
    diffusion_fused<<<grid, block, 0, stream>>>(ws, out);
}

// Round 3
// 661.826 us; speedup vs baseline: 2.1977x; 1.7415x over previous
//
#include <hip/hip_runtime.h>

#define D0 64
#define D1 1024
#define D2 1024
#define KST 5                 // fused timesteps per pass
#define E   32                // working tile extent (incl. halo)
#define TT  22                // valid output tile = E - 2*KST
#define NTL 47                // ceil(D1/TT)
#define COEFF 0.05f           // ALPHA * DT
#define CHALF 0.025f          // COEFF * 0.5
#define PLANE ((size_t)D1 * (size_t)D2)

typedef float4 f4;

struct TrueT  { static constexpr bool value = true;  };
struct FalseT { static constexpr bool value = false; };

__device__ __forceinline__ f4 ld4(const float* p) { return *(const f4*)p; }
__device__ __forceinline__ void st4(float* p, f4 v) { *(f4*)p = v; }
__device__ __forceinline__ int clampi(int v, int lo, int hi) {
    v = v < lo ? lo : v; return v > hi ? hi : v;
}

// lane i <- lane i-1 (row_shr:1). Invalid lanes (lane%16==0) are c4==0 garbage cols.
__device__ __forceinline__ float dpp_shr1(float x) {
    return __int_as_float(__builtin_amdgcn_update_dpp(0, __float_as_int(x), 0x111, 0xf, 0xf, true));
}
// lane i <- lane i+1 (row_shl:1). Invalid lanes (lane%16==15) are c4==28 garbage cols.
__device__ __forceinline__ float dpp_shl1(float x) {
    return __int_as_float(__builtin_amdgcn_update_dpp(0, __float_as_int(x), 0x101, 0xf, 0xf, true));
}

// One stencil update of a 1x4 run. All boundary scale/value handling is folded
// into precomputed csy / cx / clamped offsets; x-edge value fixups only if FIX2.
template<bool FIX2>
__device__ __forceinline__ f4 sten(f4 c, f4 zm, f4 zp, f4 um, f4 dn,
                                   float csy, f4 cx, float czf, int xlo, int xhi) {
    f4 xm = make_float4(dpp_shr1(c.w), c.x, c.y, c.z);
    f4 xp = make_float4(c.y, c.z, c.w, dpp_shl1(c.x));
    if (FIX2) {
        if (xlo == 0) xm.x = c.x;
        if (xlo == 1) xm.y = c.y;
        if (xlo == 2) xm.z = c.z;
        if (xlo == 3) xm.w = c.w;
        if (xhi == 0) xp.x = c.x;
        if (xhi == 1) xp.y = c.y;
        if (xhi == 2) xp.z = c.z;
        if (xhi == 3) xp.w = c.w;
    }
    f4 o;
    o.x = c.x + cx.x * (xp.x - xm.x) + csy * (dn.x - um.x) + czf * (zp.x - zm.x);
    o.y = c.y + cx.y * (xp.y - xm.y) + csy * (dn.y - um.y) + czf * (zp.y - zm.y);
    o.z = c.z + cx.z * (xp.z - xm.z) + csy * (dn.z - um.z) + czf * (zp.z - zm.z);
    o.w = c.w + cx.w * (xp.w - xm.w) + csy * (dn.w - um.w) + czf * (zp.w - zm.w);
    return o;
}

// LDS layout (planes of E*E floats):
//   planes 0..1   : input ring (2 slots, plane p at slot p&1)
//   planes 2+4(s-1)+k, k=0..3 : stage-s output ring (s=1..4), plane p at slot p&3
// Schedule: stage s computes plane p_s = t+1-2s at iteration t (lag-2).
template<bool FIX2>
__device__ __forceinline__ void run(const float* __restrict__ src, float* __restrict__ dst,
                                    float* lds, int r, int c4, int h1, int h2) {
    const int g1 = h1 + r;
    const int off_c = r * E + c4;
    const int up_r = (r == 0     || g1 <= 0)      ? r : r - 1;   // clamped: tile edge & global edge
    const int dn_r = (r == E - 1 || g1 >= D1 - 1) ? r : r + 1;
    const int off_up = up_r * E + c4;
    const int off_dn = dn_r * E + c4;
    const float csy = (g1 == 0 || g1 == D1 - 1) ? COEFF : CHALF;

    f4 cx;
    {
        const int gb = h2 + c4;
        cx.x = (gb + 0 == 0 || gb + 0 == D2 - 1) ? COEFF : CHALF;
        cx.y = (gb + 1 == 0 || gb + 1 == D2 - 1) ? COEFF : CHALF;
        cx.z = (gb + 2 == 0 || gb + 2 == D2 - 1) ? COEFF : CHALF;
        cx.w = (gb + 3 == 0 || gb + 3 == D2 - 1) ? COEFF : CHALF;
    }
    int xlo = -1, xhi = -1;
    if (FIX2) {
        const int a = -(h2 + c4);            // elem with g2 == 0
        const int b = (D2 - 1) - (h2 + c4);  // elem with g2 == D2-1
        if (a >= 0 && a < 4) xlo = a;
        if (b >= 0 && b < 4) xhi = b;
    }

    // global load setup (row-clamped; col-clamped only in FIX2 blocks)
    const int gr = clampi(g1, 0, D1 - 1);
    const float* gbase = src + (size_t)gr * D2;
    int gc0 = 0, gc1 = 0, gc2 = 0, gc3 = 0, gofs = 0;
    if (FIX2) {
        gc0 = clampi(h2 + c4 + 0, 0, D2 - 1);
        gc1 = clampi(h2 + c4 + 1, 0, D2 - 1);
        gc2 = clampi(h2 + c4 + 2, 0, D2 - 1);
        gc3 = clampi(h2 + c4 + 3, 0, D2 - 1);
    } else {
        gofs = h2 + c4;
    }
    auto gload = [&](int zi) -> f4 {
        const float* p = gbase + (size_t)zi * PLANE;
        if (FIX2) return make_float4(p[gc0], p[gc1], p[gc2], p[gc3]);
        return ld4(p + gofs);
    };

    // store setup
    const bool rowok = (r >= KST && r <= E - 1 - KST);
    float* drow = dst + (size_t)g1 * D2 + h2;   // only used when rowok (g1 in range)

    // state: input z-lags + per-stage output z-lags (all registers)
    f4 l1, l2, nxt, nx2;
    f4 s1l0, s1l1, s1l2, s2l0, s2l1, s2l2, s3l0, s3l1, s3l2, s4l0, s4l1, s4l2;

    // ---- pre-loop (t = 0): commit plane 0, prefetch planes 1,2 ----
    {
        f4 a = gload(0);
        st4(lds + off_c, a);                  // ring0 slot 0
        l1 = a; l2 = a;
        nxt = gload(1);
        nx2 = gload(2);
        s1l0 = s1l1 = s1l2 = a;
        s2l0 = s2l1 = s2l2 = a;
        s3l0 = s3l1 = s3l2 = a;
        s4l0 = s4l1 = s4l2 = a;
        __syncthreads();
    }

    auto body = [&](int t, int tu, auto SC) __attribute__((always_inline)) {
        constexpr bool steady = SC.value;

        // distance-2 global prefetch (plane t+2)
        f4 tmp = nx2;
        if (steady || t <= 61) tmp = gload(t + 2);

        f4 nv1 = s1l0, nv2 = s2l0, nv3 = s3l0, nv4 = s4l0;

        // ---- stage 1: input (regs + ring0 up/dn) -> ring1 ----
        if (steady || t <= 64) {                       // t >= 1 always
            const int p = t - 1;
            f4 c  = l1;
            f4 zm = (!steady && p == 0)      ? c : l2;
            f4 zp = (!steady && p == D0 - 1) ? c : nxt;
            const float czf = (!steady && (p == 0 || p == D0 - 1)) ? COEFF : CHALF;
            const int rs = steady ? ((tu + 1) & 1) : ((t - 1) & 1);
            const float* pl = lds + rs * (E * E);
            f4 um = ld4(pl + off_up), dn = ld4(pl + off_dn);
            nv1 = sten<FIX2>(c, zm, zp, um, dn, csy, cx, czf, xlo, xhi);
            const int ws = steady ? ((tu + 15) & 3) : (p & 3);
            st4(lds + (2 + ws) * (E * E) + off_c, nv1);
        }

#define STG(S, L0, L1r, L2r, NV)                                                      \
        if (steady || (t >= 2 * (S) - 1 && t <= 62 + 2 * (S))) {                      \
            const int p = t + 1 - 2 * (S);                                            \
            f4 c  = (L1r);                                                            \
            f4 zm = (!steady && p == 0)      ? c : (L2r);                             \
            f4 zp = (!steady && p == D0 - 1) ? c : (L0);                              \
            const float czf = (!steady && (p == 0 || p == D0 - 1)) ? COEFF : CHALF;   \
            const int sl = steady ? ((tu + 17 - 2 * (S)) & 3) : (p & 3);              \
            const float* pl = lds + (2 + ((S) - 2) * 4 + sl) * (E * E);               \
            f4 um = ld4(pl + off_up), dn = ld4(pl + off_dn);                          \
            NV = sten<FIX2>(c, zm, zp, um, dn, csy, cx, czf, xlo, xhi);               \
            st4(lds + (2 + ((S) - 1) * 4 + sl) * (E * E) + off_c, NV);                \
        }
        STG(2, s1l0, s1l1, s1l2, nv2)
        STG(3, s2l0, s2l1, s2l2, nv3)
        STG(4, s3l0, s3l1, s3l2, nv4)
#undef STG

        // ---- stage 5: ring4 up/dn + s4 lags -> global ----
        if (steady || t >= 9) {                        // t <= 72 by loop bound
            const int p = t - 9;
            f4 c  = s4l1;
            f4 zm = (!steady && p == 0)      ? c : s4l2;
            f4 zp = (!steady && p == D0 - 1) ? c : s4l0;
            const float czf = (!steady && (p == 0 || p == D0 - 1)) ? COEFF : CHALF;
            const int sl = steady ? ((tu + 7) & 3) : (p & 3);
            const float* pl = lds + (14 + sl) * (E * E);
            f4 um = ld4(pl + off_up), dn = ld4(pl + off_dn);
            f4 o = sten<FIX2>(c, zm, zp, um, dn, csy, cx, czf, xlo, xhi);
            if (rowok) {
                float* dp = drow + (size_t)p * PLANE;
                if (c4 >= 8 && c4 <= 20) {
                    st4(dp + c4, o);
                } else if (c4 == 4) {
                    dp[5] = o.y; *(float2*)(dp + 6) = make_float2(o.z, o.w);
                } else if (c4 == 24) {
                    *(float2*)(dp + 24) = make_float2(o.x, o.y); dp[26] = o.z;
                }
            }
        }

        // ---- commit input plane t, roll all lags ----
        if (steady || t <= 63) {
            const int ws0 = steady ? (tu & 1) : (t & 1);
            st4(lds + ws0 * (E * E) + off_c, nxt);
        }
        l2 = l1; l1 = nxt; nxt = nx2; nx2 = tmp;
        s1l2 = s1l1; s1l1 = s1l0; s1l0 = nv1;
        s2l2 = s2l1; s2l1 = s2l0; s2l0 = nv2;
        s3l2 = s3l1; s3l1 = s3l0; s3l0 = nv3;
        s4l2 = s4l1; s4l1 = s4l0; s4l0 = nv4;
        __syncthreads();
    };

    // prologue (generic guards, runtime slots)
#pragma unroll 1
    for (int t = 1; t <= 11; ++t) body(t, t & 3, FalseT{});
    // steady state: all stages active, z-interior, unroll x4 -> compile-time slots
#pragma unroll 1
    for (int t = 12; t < 60; t += 4) {
        body(t + 0, 0, TrueT{});
        body(t + 1, 1, TrueT{});
        body(t + 2, 2, TrueT{});
        body(t + 3, 3, TrueT{});
    }
    // epilogue
#pragma unroll 1
    for (int t = 60; t <= 72; ++t) body(t, t & 3, FalseT{});
}

__global__ __launch_bounds__(256, 2) void diffusion_fused(const float* __restrict__ src,
                                                          float* __restrict__ dst) {
    __shared__ __align__(16) float lds[18 * E * E];   // 73728 B -> 2 blocks/CU

    const int b = blockIdx.x;
    const int bt1 = b / NTL;
    const int bt2 = b - bt1 * NTL;
    const int o1 = min(bt1 * TT, D1 - TT);
    const int o2 = min(bt2 * TT, D2 - TT);
    const int h1 = o1 - KST;
    const int h2 = o2 - KST;

    const int r  = threadIdx.x >> 3;          // 0..31
    const int c4 = (threadIdx.x & 7) << 2;    // 0,4,...,28

    if (o2 == 0 || o2 == D2 - TT) run<true >(src, dst, &lds[0], r, c4, h1, h2);
    else                          run<false>(src, dst, &lds[0], r, c4, h1, h2);
}

extern "C" void kernel_launch(void* const* d_in, const int* in_sizes, int n_in,
                              void* d_out, int out_size, void* d_ws, size_t ws_size,
                              hipStream_t stream) {
    const float* x   = (const float*)d_in[0];
    float*       out = (float*)d_out;
    float*       ws  = (float*)d_ws;

    const dim3 grid(NTL * NTL);   // 2209 blocks
    const dim3 block(256);

    // 10 steps = 2 fused passes of 5
    diffusion_fused<<<grid, block, 0, stream>>>(x, ws);
    diffusion_fused<<<grid, block, 0, stream>>>(ws, out);
}

// Round 4
// 509.776 us; speedup vs baseline: 2.8532x; 1.2983x over previous
//
#include <hip/hip_runtime.h>

#define D0 64
#define D1 1024
#define D2 1024
#define KST 5
#define W   32                 // d2 strip width incl. 2*KST halo
#define TT  22                 // valid strip width
#define NSTRIP 47
#define NSEG 10
#define SEGLEN 103             // ceil(1024/10)
#define COEFF 0.05f
#define CHALF 0.025f
#define PS (D0 * W)            // floats per LDS plane (2048)
#define ROWSTR ((size_t)D1 * (size_t)D2)   // d0 stride in floats

typedef float4 f4;

struct PG { static constexpr bool steady = false; static constexpr int par = 0; };
struct P0 { static constexpr bool steady = true;  static constexpr int par = 0; };
struct P1 { static constexpr bool steady = true;  static constexpr int par = 1; };

__device__ __forceinline__ f4 ld4(const float* p) { return *(const f4*)p; }
__device__ __forceinline__ void st4(float* p, f4 v) { *(f4*)p = v; }
__device__ __forceinline__ int clampi(int v, int lo, int hi) {
    v = v < lo ? lo : v; return v > hi ? hi : v;
}

// lane i <- lane i-1 (row_shr:1). Invalid at lane%16==0 -> c4==0 garbage col.
__device__ __forceinline__ float dpp_shr1(float x) {
    return __int_as_float(__builtin_amdgcn_update_dpp(0, __float_as_int(x), 0x111, 0xf, 0xf, true));
}
// lane i <- lane i+1 (row_shl:1). Invalid at lane%16==15 -> c4==28 garbage col.
__device__ __forceinline__ float dpp_shl1(float x) {
    return __int_as_float(__builtin_amdgcn_update_dpp(0, __float_as_int(x), 0x101, 0xf, 0xf, true));
}

// Stencil on a 1x4 run. x-axis = d2 (DPP + cx coeffs), row axis = d0 (um/dn +
// csr), stream axis = d1 (zm/zp + czf). Boundary semantics: one-sided (coeff
// COEFF) at global edges via clamped values, central (CHALF) inside.
template<bool FIX2>
__device__ __forceinline__ f4 sten(f4 c, f4 zm, f4 zp, f4 um, f4 dn,
                                   float csr, f4 cx, float czf, int xlo, int xhi) {
    f4 xm = make_float4(dpp_shr1(c.w), c.x, c.y, c.z);
    f4 xp = make_float4(c.y, c.z, c.w, dpp_shl1(c.x));
    if (FIX2) {
        if (xlo == 0) xm.x = c.x;
        if (xlo == 1) xm.y = c.y;
        if (xlo == 2) xm.z = c.z;
        if (xlo == 3) xm.w = c.w;
        if (xhi == 0) xp.x = c.x;
        if (xhi == 1) xp.y = c.y;
        if (xhi == 2) xp.z = c.z;
        if (xhi == 3) xp.w = c.w;
    }
    f4 o;
    o.x = c.x + cx.x * (xp.x - xm.x) + csr * (dn.x - um.x) + czf * (zp.x - zm.x);
    o.y = c.y + cx.y * (xp.y - xm.y) + csr * (dn.y - um.y) + czf * (zp.y - zm.y);
    o.z = c.z + cx.z * (xp.z - xm.z) + csr * (dn.z - um.z) + czf * (zp.z - zm.z);
    o.w = c.w + cx.w * (xp.w - xm.w) + csr * (dn.w - um.w) + czf * (zp.w - zm.w);
    return o;
}

// LDS: 10 planes of PS floats. Planes 0,1 = input ring; 2+2(s-1)+k (k=0,1) =
// stage-s ring. Lag-1 schedule: at iter t, stage s computes d1-plane p = t-s;
// c/zm come from stage s-1's lag regs (same thread, same row), zp from stage
// s-1's output THIS iteration (program order), up/dn rows from ring[s-1]
// written last iteration. One __syncthreads per iter.
template<bool FIX2>
__device__ __forceinline__ void run(const float* __restrict__ src, float* __restrict__ dst,
                                    float* lds, int r, int c4, int h2, int a, int bE) {
    const int off_c  = r * W + c4;
    const int off_up = (r == 0      ? 0      : r - 1) * W + c4;
    const int off_dn = (r == D0 - 1 ? D0 - 1 : r + 1) * W + c4;
    const float csr = (r == 0 || r == D0 - 1) ? COEFF : CHALF;

    f4 cx;
    {
        const int gb = h2 + c4;
        cx.x = (gb + 0 == 0 || gb + 0 == D2 - 1) ? COEFF : CHALF;
        cx.y = (gb + 1 == 0 || gb + 1 == D2 - 1) ? COEFF : CHALF;
        cx.z = (gb + 2 == 0 || gb + 2 == D2 - 1) ? COEFF : CHALF;
        cx.w = (gb + 3 == 0 || gb + 3 == D2 - 1) ? COEFF : CHALF;
    }
    int xlo = -1, xhi = -1;
    if (FIX2) {
        const int aa = -(h2 + c4);
        const int bb = (D2 - 1) - (h2 + c4);
        if (aa >= 0 && aa < 4) xlo = aa;
        if (bb >= 0 && bb < 4) xhi = bb;
    }

    // global load setup (rows never out of range; cols clamped only in FIX2)
    const float* gbase = src + (size_t)r * ROWSTR;
    int gc0 = 0, gc1 = 0, gc2 = 0, gc3 = 0, gofs = 0;
    if (FIX2) {
        gc0 = clampi(h2 + c4 + 0, 0, D2 - 1);
        gc1 = clampi(h2 + c4 + 1, 0, D2 - 1);
        gc2 = clampi(h2 + c4 + 2, 0, D2 - 1);
        gc3 = clampi(h2 + c4 + 3, 0, D2 - 1);
    } else {
        gofs = h2 + c4;
    }
    auto gload = [&](int p) -> f4 {
        const float* pp = gbase + (size_t)p * D2;
        if (FIX2) return make_float4(pp[gc0], pp[gc1], pp[gc2], pp[gc3]);
        return ld4(pp + gofs);
    };

    float* dbase = dst + (size_t)r * ROWSTR + h2;

    // stage activity windows (block-uniform -> SGPRs)
    const int t0  = max(a - KST, 0);
    const int hiIn = min(bE + KST, D1);
    const int lo1 = max(a - 4, 0), hi1 = min(bE + 4, D1);
    const int lo2 = max(a - 3, 0), hi2 = min(bE + 3, D1);
    const int lo3 = max(a - 2, 0), hi3 = min(bE + 2, D1);
    const int lo4 = max(a - 1, 0), hi4 = min(bE + 1, D1);
    const int lo5 = a,             hi5 = bE;

    // register state
    f4 l0, l1, nxt, nx2;
    f4 s1l0, s1l1, s2l0, s2l1, s3l0, s3l1, s4l0, s4l1;

    nxt = gload(t0);
    nx2 = gload(min(t0 + 1, D1 - 1));
    l0 = l1 = nxt;
    s1l0 = s1l1 = s2l0 = s2l1 = nxt;
    s3l0 = s3l1 = s4l0 = s4l1 = nxt;

    auto body = [&](int t, auto TAG) __attribute__((always_inline)) {
        constexpr bool ST = decltype(TAG)::steady;
        constexpr int PAR = decltype(TAG)::par;

        f4 tmp = gload(min(t + 2, D1 - 1));   // distance-2 prefetch

        f4 nv1 = s1l0, nv2 = s2l0, nv3 = s3l0, nv4 = s4l0;

        // ---- stage 1: input regs + ring0 up/dn -> ring1 ----
        if (ST || (t - 1 >= lo1 && t - 1 < hi1)) {
            const int p = t - 1;
            const int sl = ST ? (PAR ^ 1) : (p & 1);
            f4 c  = l0;
            f4 zm = (!ST && p == 0)      ? c : l1;
            f4 zp = (!ST && p == D1 - 1) ? c : nxt;
            const float czf = (!ST && (p == 0 || p == D1 - 1)) ? COEFF : CHALF;
            const float* pl = lds + sl * PS;
            f4 um = ld4(pl + off_up), dn = ld4(pl + off_dn);
            nv1 = sten<FIX2>(c, zm, zp, um, dn, csr, cx, czf, xlo, xhi);
            st4(lds + (2 + sl) * PS + off_c, nv1);
        }

#define SG(S, L0v, L1v, NVp, NV)                                                 \
        if (ST || (t - (S) >= lo##S && t - (S) < hi##S)) {                       \
            const int p = t - (S);                                               \
            const int sl = ST ? (PAR ^ ((S) & 1)) : (p & 1);                     \
            f4 c  = L0v;                                                         \
            f4 zm = (!ST && p == 0)      ? c : L1v;                              \
            f4 zp = (!ST && p == D1 - 1) ? c : NVp;                              \
            const float czf = (!ST && (p == 0 || p == D1 - 1)) ? COEFF : CHALF;  \
            const float* pl = lds + (2 * ((S) - 1) + sl) * PS;                   \
            f4 um = ld4(pl + off_up), dn = ld4(pl + off_dn);                     \
            NV = sten<FIX2>(c, zm, zp, um, dn, csr, cx, czf, xlo, xhi);          \
            st4(lds + (2 * (S) + sl) * PS + off_c, NV);                          \
        }
        SG(2, s1l0, s1l1, nv1, nv2)
        SG(3, s2l0, s2l1, nv2, nv3)
        SG(4, s3l0, s3l1, nv3, nv4)
#undef SG

        // ---- stage 5: ring4 up/dn + s4 lags -> global ----
        if (ST || (t - 5 >= lo5 && t - 5 < hi5)) {
            const int p = t - 5;
            const int sl = ST ? (PAR ^ 1) : (p & 1);
            f4 c  = s4l0;
            f4 zm = (!ST && p == 0)      ? c : s4l1;
            f4 zp = (!ST && p == D1 - 1) ? c : nv4;
            const float czf = (!ST && (p == 0 || p == D1 - 1)) ? COEFF : CHALF;
            const float* pl = lds + (8 + sl) * PS;
            f4 um = ld4(pl + off_up), dn = ld4(pl + off_dn);
            f4 o = sten<FIX2>(c, zm, zp, um, dn, csr, cx, czf, xlo, xhi);
            float* dp = dbase + (size_t)p * D2;
            if (c4 >= 8 && c4 <= 20) {
                st4(dp + c4, o);
            } else if (c4 == 4) {
                dp[5] = o.y; *(float2*)(dp + 6) = make_float2(o.z, o.w);
            } else if (c4 == 24) {
                *(float2*)(dp + 24) = make_float2(o.x, o.y); dp[26] = o.z;
            }
        }

        // ---- commit input plane t ----
        if (ST || t < hiIn) st4(lds + (ST ? PAR : (t & 1)) * PS + off_c, nxt);

        // ---- roll lags ----
        l1 = l0; l0 = nxt; nxt = nx2; nx2 = tmp;
        s1l1 = s1l0; s1l0 = nv1;
        s2l1 = s2l0; s2l0 = nv2;
        s3l1 = s3l0; s3l0 = nv3;
        s4l1 = s4l0; s4l0 = nv4;
        __syncthreads();
    };

    int tSlo = t0 + 11; tSlo += (tSlo & 1);           // even steady entry
    const int tEnd = bE + 4;
    const int tShi = min(bE + 4, D1 - 1);
    int t = t0;
    const int tP = min(tSlo, tEnd + 1);
#pragma unroll 1
    for (; t < tP; ++t) body(t, PG{});
#pragma unroll 1
    for (; t + 1 <= tShi; t += 2) { body(t, P0{}); body(t + 1, P1{}); }
#pragma unroll 1
    for (; t <= tEnd; ++t) body(t, PG{});
}

__global__ __launch_bounds__(512, 4) void diffusion_fused(const float* __restrict__ src,
                                                          float* __restrict__ dst) {
    __shared__ __align__(16) float lds[10 * PS];   // 81920 B -> 2 blocks/CU

    const int b = blockIdx.x;
    const int seg = b / NSTRIP;
    const int strip = b - seg * NSTRIP;
    const int o2 = min(strip * TT, D2 - TT);
    const int h2 = o2 - KST;
    const int a  = seg * SEGLEN;
    const int bE = min(a + SEGLEN, D1);

    const int r  = threadIdx.x >> 3;          // 0..63 over d0 (no halo)
    const int c4 = (threadIdx.x & 7) << 2;    // 0..28 over d2 strip

    if (o2 == 0 || o2 == D2 - TT) run<true >(src, dst, &lds[0], r, c4, h2, a, bE);
    else                          run<false>(src, dst, &lds[0], r, c4, h2, a, bE);
}

extern "C" void kernel_launch(void* const* d_in, const int* in_sizes, int n_in,
                              void* d_out, int out_size, void* d_ws, size_t ws_size,
                              hipStream_t stream) {
    const float* x   = (const float*)d_in[0];
    float*       out = (float*)d_out;
    float*       ws  = (float*)d_ws;

    const dim3 grid(NSTRIP * NSEG);   // 470 blocks
    const dim3 block(512);

    diffusion_fused<<<grid, block, 0, stream>>>(x, ws);
    diffusion_fused<<<grid, block, 0, stream>>>(ws, out);
}

// Round 5
// 475.217 us; speedup vs baseline: 3.0607x; 1.0727x over previous
//
#include <hip/hip_runtime.h>

#define D0 64
#define D1 1024
#define D2 1024
#define KST 5
#define W   32                 // d2 strip width incl. 2*KST halo
#define TT  22                 // valid strip width
#define NSTRIP 47
#define NSEG 10
#define SEGLEN 103
#define NWG (NSTRIP * NSEG)    // 470
#define COEFF 0.05f
#define CHALF 0.025f
#define PS2 (D0 * W / 2)       // u32 (bf16x2) per LDS plane = 1024
#define ROWSTR ((size_t)D1 * (size_t)D2)

typedef float4 f4;
typedef unsigned int u32;
typedef unsigned short u16;

struct PG { static constexpr bool steady = false; static constexpr int par = 0; };
struct P0 { static constexpr bool steady = true;  static constexpr int par = 0; };
struct P1 { static constexpr bool steady = true;  static constexpr int par = 1; };

__device__ __forceinline__ f4 ld4(const float* p) { return *(const f4*)p; }
__device__ __forceinline__ void st4(float* p, f4 v) { *(f4*)p = v; }
__device__ __forceinline__ int clampi(int v, int lo, int hi) {
    v = v < lo ? lo : v; return v > hi ? hi : v;
}

// ---- bf16 pack/unpack (truncation for LDS rings; neighbor weight <= 0.05) ----
__device__ __forceinline__ u32 pk(float a, float b) {
    return (__float_as_uint(a) >> 16) | (__float_as_uint(b) & 0xFFFF0000u);
}
__device__ __forceinline__ uint2 pk4(f4 v) { return make_uint2(pk(v.x, v.y), pk(v.z, v.w)); }
__device__ __forceinline__ f4 upk4(uint2 w) {
    return make_float4(__uint_as_float(w.x << 16), __uint_as_float(w.x & 0xFFFF0000u),
                       __uint_as_float(w.y << 16), __uint_as_float(w.y & 0xFFFF0000u));
}
__device__ __forceinline__ f4 ldb(const u32* p) { return upk4(*(const uint2*)p); }
__device__ __forceinline__ void stb(u32* p, f4 v) { *(uint2*)p = pk4(v); }
__device__ __forceinline__ float bf2f(u16 h) { return __uint_as_float((u32)h << 16); }
__device__ __forceinline__ u16 f2bf(float f) {      // RTNE (full-weight reuse in pass 2)
    u32 u = __float_as_uint(f);
    u += 0x7FFFu + ((u >> 16) & 1u);
    return (u16)(u >> 16);
}

// m204 bijective XCD-chunk swizzle, nwg=470 (q=58, r=6): consecutive logical
// tiles (adjacent d2 strips) land on the same XCD -> halo reads hit L2, and
// partial-line bf16 writes combine in L2.
__device__ __forceinline__ int swz(int orig) {
    const int xcd = orig & 7, sub = orig >> 3;
    const int base = (xcd < 6) ? xcd * 59 : 354 + (xcd - 6) * 58;
    return base + sub;
}

// lane i <- lane i-1 (row_shr:1). Invalid at lane%16==0 -> c4==0 garbage col.
__device__ __forceinline__ float dpp_shr1(float x) {
    return __int_as_float(__builtin_amdgcn_update_dpp(0, __float_as_int(x), 0x111, 0xf, 0xf, true));
}
// lane i <- lane i+1 (row_shl:1). Invalid at lane%16==15 -> c4==28 garbage col.
__device__ __forceinline__ float dpp_shl1(float x) {
    return __int_as_float(__builtin_amdgcn_update_dpp(0, __float_as_int(x), 0x101, 0xf, 0xf, true));
}

template<bool FIX2>
__device__ __forceinline__ f4 sten(f4 c, f4 zm, f4 zp, f4 um, f4 dn,
                                   float csr, f4 cx, float czf, int xlo, int xhi) {
    f4 xm = make_float4(dpp_shr1(c.w), c.x, c.y, c.z);
    f4 xp = make_float4(c.y, c.z, c.w, dpp_shl1(c.x));
    if (FIX2) {
        if (xlo == 0) xm.x = c.x;
        if (xlo == 1) xm.y = c.y;
        if (xlo == 2) xm.z = c.z;
        if (xlo == 3) xm.w = c.w;
        if (xhi == 0) xp.x = c.x;
        if (xhi == 1) xp.y = c.y;
        if (xhi == 2) xp.z = c.z;
        if (xhi == 3) xp.w = c.w;
    }
    f4 o;
    o.x = c.x + cx.x * (xp.x - xm.x) + csr * (dn.x - um.x) + czf * (zp.x - zm.x);
    o.y = c.y + cx.y * (xp.y - xm.y) + csr * (dn.y - um.y) + czf * (zp.y - zm.y);
    o.z = c.z + cx.z * (xp.z - xm.z) + csr * (dn.z - um.z) + czf * (zp.z - zm.z);
    o.w = c.w + cx.w * (xp.w - xm.w) + csr * (dn.w - um.w) + czf * (zp.w - zm.w);
    return o;
}

// PASS 0: f32 src -> bf16 ws.  PASS 1: bf16 ws -> f32 dst.
// LDS: 10 bf16 planes (u32-packed). Planes 0,1 = input ring; 2+2(s-1)+k =
// stage-s ring. Lag-1: at iter t stage s computes d1-plane p = t-s.
template<int PASS, bool FIX2>
__device__ __forceinline__ void run(const void* __restrict__ srcv, void* __restrict__ dstv,
                                    u32* lds, int r, int c4, int h2, int a, int bE) {
    const float* srcf = (const float*)srcv;
    const u16*   srch = (const u16*)srcv;
    u16*   dsth = (u16*)dstv;
    float* dstf = (float*)dstv;

    const int off_c  = r * (W / 2) + (c4 >> 1);
    const int off_up = ((r == 0      ? 0      : r - 1)) * (W / 2) + (c4 >> 1);
    const int off_dn = ((r == D0 - 1 ? D0 - 1 : r + 1)) * (W / 2) + (c4 >> 1);
    const float csr = (r == 0 || r == D0 - 1) ? COEFF : CHALF;

    f4 cx;
    {
        const int gb = h2 + c4;
        cx.x = (gb + 0 == 0 || gb + 0 == D2 - 1) ? COEFF : CHALF;
        cx.y = (gb + 1 == 0 || gb + 1 == D2 - 1) ? COEFF : CHALF;
        cx.z = (gb + 2 == 0 || gb + 2 == D2 - 1) ? COEFF : CHALF;
        cx.w = (gb + 3 == 0 || gb + 3 == D2 - 1) ? COEFF : CHALF;
    }
    int xlo = -1, xhi = -1;
    if (FIX2) {
        const int aa = -(h2 + c4);
        const int bb = (D2 - 1) - (h2 + c4);
        if (aa >= 0 && aa < 4) xlo = aa;
        if (bb >= 0 && bb < 4) xhi = bb;
    }

    int gc0, gc1, gc2, gc3;
    if (FIX2) {
        gc0 = clampi(h2 + c4 + 0, 0, D2 - 1);
        gc1 = clampi(h2 + c4 + 1, 0, D2 - 1);
        gc2 = clampi(h2 + c4 + 2, 0, D2 - 1);
        gc3 = clampi(h2 + c4 + 3, 0, D2 - 1);
    } else {
        gc0 = h2 + c4; gc1 = gc0 + 1; gc2 = gc0 + 2; gc3 = gc0 + 3;
    }
    auto gload = [&](int p) -> f4 {
        if (PASS == 0) {
            const float* pp = srcf + (size_t)r * ROWSTR + (size_t)p * D2;
            if (FIX2) return make_float4(pp[gc0], pp[gc1], pp[gc2], pp[gc3]);
            return ld4(pp + gc0);
        } else {
            const u16* pp = srch + (size_t)r * ROWSTR + (size_t)p * D2;
            return make_float4(bf2f(pp[gc0]), bf2f(pp[gc1]), bf2f(pp[gc2]), bf2f(pp[gc3]));
        }
    };

    u16*   dbh = dsth + (size_t)r * ROWSTR + h2;
    float* dbf = dstf + (size_t)r * ROWSTR + h2;

    const int t0   = max(a - KST, 0);
    const int hiIn = min(bE + KST, D1);
    const int lo1 = max(a - 4, 0), hi1 = min(bE + 4, D1);
    const int lo2 = max(a - 3, 0), hi2 = min(bE + 3, D1);
    const int lo3 = max(a - 2, 0), hi3 = min(bE + 2, D1);
    const int lo4 = max(a - 1, 0), hi4 = min(bE + 1, D1);
    const int lo5 = a,             hi5 = bE;

    f4 l0, l1, nxt, nx2;
    f4 s1l0, s1l1, s2l0, s2l1, s3l0, s3l1, s4l0, s4l1;

    nxt = gload(t0);
    nx2 = gload(min(t0 + 1, D1 - 1));
    l0 = l1 = nxt;
    s1l0 = s1l1 = s2l0 = s2l1 = nxt;
    s3l0 = s3l1 = s4l0 = s4l1 = nxt;

    auto body = [&](int t, auto TAG) __attribute__((always_inline)) {
        constexpr bool ST = decltype(TAG)::steady;
        constexpr int PAR = decltype(TAG)::par;

        f4 tmp = gload(min(t + 2, D1 - 1));   // distance-2 prefetch

        f4 nv1 = s1l0, nv2 = s2l0, nv3 = s3l0, nv4 = s4l0;

        // ---- stage 1: input regs + ring0 up/dn -> ring1 ----
        if (ST || (t - 1 >= lo1 && t - 1 < hi1)) {
            const int p = t - 1;
            const int sl = ST ? (PAR ^ 1) : (p & 1);
            f4 c  = l0;
            f4 zm = (!ST && p == 0)      ? c : l1;
            f4 zp = (!ST && p == D1 - 1) ? c : nxt;
            const float czf = (!ST && (p == 0 || p == D1 - 1)) ? COEFF : CHALF;
            const u32* pl = lds + sl * PS2;
            f4 um = ldb(pl + off_up), dn = ldb(pl + off_dn);
            nv1 = sten<FIX2>(c, zm, zp, um, dn, csr, cx, czf, xlo, xhi);
            stb(lds + (2 + sl) * PS2 + off_c, nv1);
        }

#define SG(S, L0v, L1v, NVp, NV)                                                 \
        if (ST || (t - (S) >= lo##S && t - (S) < hi##S)) {                       \
            const int p = t - (S);                                               \
            const int sl = ST ? (PAR ^ ((S) & 1)) : (p & 1);                     \
            f4 c  = L0v;                                                         \
            f4 zm = (!ST && p == 0)      ? c : L1v;                              \
            f4 zp = (!ST && p == D1 - 1) ? c : NVp;                              \
            const float czf = (!ST && (p == 0 || p == D1 - 1)) ? COEFF : CHALF;  \
            const u32* pl = lds + (2 * ((S) - 1) + sl) * PS2;                    \
            f4 um = ldb(pl + off_up), dn = ldb(pl + off_dn);                     \
            NV = sten<FIX2>(c, zm, zp, um, dn, csr, cx, czf, xlo, xhi);          \
            stb(lds + (2 * (S) + sl) * PS2 + off_c, NV);                         \
        }
        SG(2, s1l0, s1l1, nv1, nv2)
        SG(3, s2l0, s2l1, nv2, nv3)
        SG(4, s3l0, s3l1, nv3, nv4)
#undef SG

        // ---- stage 5: ring4 up/dn + s4 lags -> global ----
        if (ST || (t - 5 >= lo5 && t - 5 < hi5)) {
            const int p = t - 5;
            const int sl = ST ? (PAR ^ 1) : (p & 1);
            f4 c  = s4l0;
            f4 zm = (!ST && p == 0)      ? c : s4l1;
            f4 zp = (!ST && p == D1 - 1) ? c : nv4;
            const float czf = (!ST && (p == 0 || p == D1 - 1)) ? COEFF : CHALF;
            const u32* pl = lds + (8 + sl) * PS2;
            f4 um = ldb(pl + off_up), dn = ldb(pl + off_dn);
            f4 o = sten<FIX2>(c, zm, zp, um, dn, csr, cx, czf, xlo, xhi);
            if (PASS == 0) {
                u16* dp = dbh + (size_t)p * D2;
                if (c4 + 0 >= 5 && c4 + 0 <= 26) dp[c4 + 0] = f2bf(o.x);
                if (c4 + 1 >= 5 && c4 + 1 <= 26) dp[c4 + 1] = f2bf(o.y);
                if (c4 + 2 >= 5 && c4 + 2 <= 26) dp[c4 + 2] = f2bf(o.z);
                if (c4 + 3 >= 5 && c4 + 3 <= 26) dp[c4 + 3] = f2bf(o.w);
            } else {
                float* dp = dbf + (size_t)p * D2;
                if (c4 >= 8 && c4 <= 20) {
                    st4(dp + c4, o);
                } else if (c4 == 4) {
                    dp[5] = o.y; *(float2*)(dp + 6) = make_float2(o.z, o.w);
                } else if (c4 == 24) {
                    *(float2*)(dp + 24) = make_float2(o.x, o.y); dp[26] = o.z;
                }
            }
        }

        // ---- commit input plane t ----
        if (ST || t < hiIn) stb(lds + (ST ? PAR : (t & 1)) * PS2 + off_c, nxt);

        // ---- roll lags ----
        l1 = l0; l0 = nxt; nxt = nx2; nx2 = tmp;
        s1l1 = s1l0; s1l0 = nv1;
        s2l1 = s2l0; s2l0 = nv2;
        s3l1 = s3l0; s3l0 = nv3;
        s4l1 = s4l0; s4l0 = nv4;
        __syncthreads();
    };

    int tSlo = t0 + 11; tSlo += (tSlo & 1);
    const int tEnd = bE + 4;
    const int tShi = min(bE + 4, D1 - 1);
    int t = t0;
    const int tP = min(tSlo, tEnd + 1);
#pragma unroll 1
    for (; t < tP; ++t) body(t, PG{});
#pragma unroll 1
    for (; t + 1 <= tShi; t += 2) { body(t, P0{}); body(t + 1, P1{}); }
#pragma unroll 1
    for (; t <= tEnd; ++t) body(t, PG{});
}

template<int PASS>
__global__ __launch_bounds__(512, 4) void diffusion_fused(const void* __restrict__ src,
                                                          void* __restrict__ dst) {
    __shared__ __align__(16) u32 lds[10 * PS2];   // 40960 B

    const int b = swz(blockIdx.x);
    const int seg = b / NSTRIP;
    const int strip = b - seg * NSTRIP;
    const int o2 = min(strip * TT, D2 - TT);
    const int h2 = o2 - KST;
    const int a  = seg * SEGLEN;
    const int bE = min(a + SEGLEN, D1);

    const int r  = threadIdx.x >> 3;
    const int c4 = (threadIdx.x & 7) << 2;

    if (o2 == 0 || o2 == D2 - TT) run<PASS, true >(src, dst, &lds[0], r, c4, h2, a, bE);
    else                          run<PASS, false>(src, dst, &lds[0], r, c4, h2, a, bE);
}

extern "C" void kernel_launch(void* const* d_in, const int* in_sizes, int n_in,
                              void* d_out, int out_size, void* d_ws, size_t ws_size,
                              hipStream_t stream) {
    const void* x  = d_in[0];
    void* out = d_out;
    void* ws  = d_ws;

    const dim3 grid(NWG);
    const dim3 block(512);

    diffusion_fused<0><<<grid, block, 0, stream>>>(x, ws);    // f32 -> bf16 ws
    diffusion_fused<1><<<grid, block, 0, stream>>>(ws, out);  // bf16 ws -> f32
}